// Round 1
// baseline (336.975 us; speedup 1.0000x reference)
//
#include <hip/hip_runtime.h>
#include <hip/hip_bf16.h>

#define DI __device__ __forceinline__

typedef __bf16 bf16x8 __attribute__((ext_vector_type(8)));
typedef float  f32x4  __attribute__((ext_vector_type(4)));

// round-to-nearest-even f32 -> bf16 (as raw u16)
DI unsigned short f2bf(float f) {
    unsigned int u = __float_as_uint(f);
    u += 0x7fffu + ((u >> 16) & 1u);
    return (unsigned short)(u >> 16);
}

DI void gload16(const unsigned short* g, unsigned short* l) {
    __builtin_amdgcn_global_load_lds(
        (const __attribute__((address_space(1))) unsigned int*)g,
        (__attribute__((address_space(3))) unsigned int*)l, 16, 0, 0);
}

// ---------------------------------------------------------------------------
// converts
// ---------------------------------------------------------------------------
__global__ void convert_x(const float* __restrict__ x, unsigned short* __restrict__ Xb) {
    int i = blockIdx.x * 256 + threadIdx.x;       // grid exactly covers 16.8M/4
    float4 v = reinterpret_cast<const float4*>(x)[i];
    ushort4 o;
    o.x = f2bf(v.x); o.y = f2bf(v.y); o.z = f2bf(v.z); o.w = f2bf(v.w);
    reinterpret_cast<ushort4*>(Xb)[i] = o;
}

// Wt[z*1024 + n][k] = W_z[k][n] * (z==0 ? 1/32 : 1)
__global__ void convert_w(const float* __restrict__ Wq, const float* __restrict__ Wk,
                          const float* __restrict__ Wv, unsigned short* __restrict__ Wt) {
    __shared__ float t[32][33];
    const int z = blockIdx.z;
    const float* W = (z == 0) ? Wq : (z == 1 ? Wk : Wv);
    const float scale = (z == 0) ? 0.03125f : 1.0f;   // 1/sqrt(1024) folded into Wq
    const int n0 = blockIdx.x * 32, k0 = blockIdx.y * 32;
    const int tx = threadIdx.x, ty = threadIdx.y;     // 32 x 8
#pragma unroll
    for (int i = 0; i < 4; ++i)
        t[ty + i * 8][tx] = W[(size_t)(k0 + ty + i * 8) * 1024 + n0 + tx];
    __syncthreads();
#pragma unroll
    for (int i = 0; i < 4; ++i)
        Wt[(size_t)(z * 1024 + n0 + ty + i * 8) * 1024 + k0 + tx] =
            f2bf(t[tx][ty + i * 8] * scale);
}

// ---------------------------------------------------------------------------
// NT GEMM template: C[m][n] = sum_k A[m][k] * Bt[n][k], bf16 in, fp32 acc.
// 128x128 tile, BK=64, 4 waves (2x2), 4x4 frags of 16x16x32 MFMA per wave.
// MODE 0: QKV projection. A=Xb[16384][1024], Bt=Wt[3072][1024].
//         epilogue: z=0 -> Q bf16, z=1 -> K bf16, z=2 -> V stored transposed.
// MODE 1: scores. per batch A=Q, Bt=K (both [2048][1024]); causal tiles only;
//         C = packed fp32 S tiles [136 per batch][128][128].
// MODE 2: PV. A = packed bf16 P tiles, Bt = Vt[b][1024][2048]; C = out fp32.
// ---------------------------------------------------------------------------
template <int MODE>
__global__ __launch_bounds__(256, 2) void gemm_nt(
    const unsigned short* __restrict__ A0, const unsigned short* __restrict__ B0,
    float* __restrict__ Cf,
    unsigned short* __restrict__ Oq, unsigned short* __restrict__ Ok,
    unsigned short* __restrict__ Ov)
{
    __shared__ alignas(16) unsigned short lsA[2][128 * 64];
    __shared__ alignas(16) unsigned short lsB[2][128 * 64];

    const int tid = threadIdx.x;
    const int bx = blockIdx.x, by = blockIdx.y, bz = blockIdx.z;

    int m0, n0, NT, triRm = 0;
    const unsigned short *Ab, *Bb;
    size_t sbase = 0;

    if constexpr (MODE == 0) {
        m0 = bx * 128; n0 = by * 128; NT = 16;
        Ab = A0; Bb = B0;
    } else if constexpr (MODE == 1) {
        const int c = bx, r = by;
        if (c > r) return;
        m0 = r * 128; n0 = c * 128; NT = 16;
        Ab = A0 + (size_t)bz * (2048u * 1024u);
        Bb = B0 + (size_t)bz * (2048u * 1024u);
        sbase = ((size_t)bz * 136 + (size_t)(r * (r + 1) / 2) + c) << 14;
    } else {
        const int r = by;
        m0 = r * 128; n0 = bx * 128; NT = 2 * (r + 1);
        triRm = r * (r + 1) / 2;
        Ab = A0 + ((size_t)bz * 136 << 14);
        Bb = B0 + (size_t)bz * (1024u * 2048u);
    }

    // stage one BK=64 tile of A and B. LDS dest is linear (global_load_lds
    // requirement); bank-conflict swizzle is applied by permuting the GLOBAL
    // source chunk: lds[row][c'] <- global[row][c' ^ (row&7)] (16B chunks).
    auto stage = [&](int buf, int kt) {
#pragma unroll
        for (int i = 0; i < 4; ++i) {
            int idx = i * 256 + tid;
            int row = idx >> 3;
            int ch = (idx & 7) ^ (row & 7);
            const unsigned short* ga;
            if constexpr (MODE == 2) {
                ga = Ab + (((size_t)(triRm + (kt >> 1))) << 14) + row * 128 +
                     ((kt & 1) << 6) + ch * 8;
            } else {
                ga = Ab + (size_t)(m0 + row) * 1024 + kt * 64 + ch * 8;
            }
            gload16(ga, &lsA[buf][idx * 8]);
            const unsigned short* gb;
            if constexpr (MODE == 2) {
                gb = Bb + (size_t)(n0 + row) * 2048 + kt * 64 + ch * 8;
            } else {
                gb = Bb + (size_t)(n0 + row) * 1024 + kt * 64 + ch * 8;
            }
            gload16(gb, &lsB[buf][idx * 8]);
        }
    };

    const int lane = tid & 63;
    const int wid = tid >> 6;
    const int wm = wid >> 1, wn = wid & 1;
    const int lr = lane & 15;      // A-row / B-col within fragment
    const int lg = lane >> 4;      // k-octet 0..3

    f32x4 acc[4][4] = {};

    stage(0, 0);
    __syncthreads();

    int cur = 0;
    for (int t = 0; t < NT; ++t) {
        if (t + 1 < NT) stage(cur ^ 1, t + 1);
#pragma unroll
        for (int kk = 0; kk < 2; ++kk) {
            bf16x8 av[4], bv[4];
#pragma unroll
            for (int i = 0; i < 4; ++i) {
                int rowL = wm * 64 + i * 16 + lr;
                int chunk = (kk * 4 + lg) ^ (rowL & 7);
                av[i] = *reinterpret_cast<const bf16x8*>(&lsA[cur][rowL * 64 + chunk * 8]);
            }
#pragma unroll
            for (int j = 0; j < 4; ++j) {
                int rowL = wn * 64 + j * 16 + lr;
                int chunk = (kk * 4 + lg) ^ (rowL & 7);
                bv[j] = *reinterpret_cast<const bf16x8*>(&lsB[cur][rowL * 64 + chunk * 8]);
            }
#pragma unroll
            for (int i = 0; i < 4; ++i)
#pragma unroll
                for (int j = 0; j < 4; ++j)
                    acc[i][j] = __builtin_amdgcn_mfma_f32_16x16x32_bf16(
                        av[i], bv[j], acc[i][j], 0, 0, 0);
        }
        __syncthreads();
        cur ^= 1;
    }

    // epilogue: D layout col=lane&15, row=(lane>>4)*4+reg
#pragma unroll
    for (int i = 0; i < 4; ++i) {
#pragma unroll
        for (int j = 0; j < 4; ++j) {
            f32x4 v = acc[i][j];
            int rl = wm * 64 + i * 16 + lg * 4;   // tile-local row of v[0]
            int cl = wn * 64 + j * 16 + lr;       // tile-local col
            if constexpr (MODE == 0) {
                int gm = m0 + rl;
                int gn = n0 + cl;
                int z = gn >> 10;
                int cin = gn & 1023;
                if (z == 2) {   // V: store transposed per batch, Vt[b][d][n]
                    int b = gm >> 11, nib = gm & 2047;
                    ushort4 h;
                    h.x = f2bf(v[0]); h.y = f2bf(v[1]); h.z = f2bf(v[2]); h.w = f2bf(v[3]);
                    *reinterpret_cast<ushort4*>(
                        &Ov[(size_t)b * (1024u * 2048u) + (size_t)cin * 2048 + nib]) = h;
                } else {
                    unsigned short* O = (z == 0) ? Oq : Ok;
#pragma unroll
                    for (int r2 = 0; r2 < 4; ++r2)
                        O[(size_t)(gm + r2) * 1024 + cin] = f2bf(v[r2]);
                }
            } else if constexpr (MODE == 1) {
#pragma unroll
                for (int r2 = 0; r2 < 4; ++r2)
                    Cf[sbase + (size_t)(rl + r2) * 128 + cl] = v[r2];
            } else {
#pragma unroll
                for (int r2 = 0; r2 < 4; ++r2)
                    Cf[(size_t)bz * (2048u * 1024u) + (size_t)(m0 + rl + r2) * 1024 +
                       (n0 + cl)] = v[r2];
            }
        }
    }
}

// ---------------------------------------------------------------------------
// row softmax over packed causal S tiles -> packed bf16 P (zero-filled to the
// 128-tile boundary). One block per (row, batch).
// ---------------------------------------------------------------------------
__global__ __launch_bounds__(256) void softmax_rows(const float* __restrict__ Sp,
                                                    unsigned short* __restrict__ Pp) {
    const int R = blockIdx.x;
    const int b = blockIdx.y;
    const int rt = R >> 7;
    const size_t tbase = ((size_t)b * 136 + (size_t)(rt * (rt + 1) / 2)) << 14;
    const int rowoff = (R & 127) * 128;
    const int tid = threadIdx.x;
    const int kend = (rt + 1) << 7;

    float vals[8];
    float m = -3.0e38f;
    int cnt = 0;
    for (int k = tid; k < kend; k += 256) {
        float s = Sp[tbase + ((size_t)(k >> 7) << 14) + rowoff + (k & 127)];
        vals[cnt++] = s;
        if (k <= R) m = fmaxf(m, s);
    }
    __shared__ float red[4];
#pragma unroll
    for (int o = 32; o > 0; o >>= 1) m = fmaxf(m, __shfl_xor(m, o));
    if ((tid & 63) == 0) red[tid >> 6] = m;
    __syncthreads();
    m = fmaxf(fmaxf(red[0], red[1]), fmaxf(red[2], red[3]));
    __syncthreads();

    float l = 0.0f;
    cnt = 0;
    for (int k = tid; k < kend; k += 256) {
        float e = (k <= R) ? __expf(vals[cnt] - m) : 0.0f;
        vals[cnt] = e;
        ++cnt;
        l += e;
    }
#pragma unroll
    for (int o = 32; o > 0; o >>= 1) l += __shfl_xor(l, o);
    if ((tid & 63) == 0) red[tid >> 6] = l;
    __syncthreads();
    l = red[0] + red[1] + red[2] + red[3];
    const float inv = 1.0f / l;

    cnt = 0;
    for (int k = tid; k < kend; k += 256)
        Pp[tbase + ((size_t)(k >> 7) << 14) + rowoff + (k & 127)] = f2bf(vals[cnt++] * inv);
}

// ---------------------------------------------------------------------------
extern "C" void kernel_launch(void* const* d_in, const int* in_sizes, int n_in,
                              void* d_out, int out_size, void* d_ws, size_t ws_size,
                              hipStream_t stream) {
    const float* x  = (const float*)d_in[0];
    const float* Wq = (const float*)d_in[1];
    const float* Wk = (const float*)d_in[2];
    const float* Wv = (const float*)d_in[3];
    float* out = (float*)d_out;

    char* p = (char*)d_ws;
    unsigned short* Xb = (unsigned short*)p; p += (size_t)16384 * 1024 * 2;  // 33.5MB
    unsigned short* Wt = (unsigned short*)p; p += (size_t)3072 * 1024 * 2;   //  6.3MB
    unsigned short* Qb = (unsigned short*)p; p += (size_t)16384 * 1024 * 2;
    unsigned short* Kb = (unsigned short*)p; p += (size_t)16384 * 1024 * 2;
    unsigned short* Vt = (unsigned short*)p; p += (size_t)16384 * 1024 * 2;
    float* Sp          = (float*)p;          p += (size_t)8 * 136 * 16384 * 4; // 71.3MB
    unsigned short* Pp = (unsigned short*)p; p += (size_t)8 * 136 * 16384 * 2; // 35.7MB

    convert_x<<<16384, 256, 0, stream>>>(x, Xb);
    convert_w<<<dim3(32, 32, 3), dim3(32, 8), 0, stream>>>(Wq, Wk, Wv, Wt);
    gemm_nt<0><<<dim3(128, 24), 256, 0, stream>>>(Xb, Wt, nullptr, Qb, Kb, Vt);
    gemm_nt<1><<<dim3(16, 16, 8), 256, 0, stream>>>(Qb, Kb, Sp, nullptr, nullptr, nullptr);
    softmax_rows<<<dim3(2048, 8), 256, 0, stream>>>(Sp, Pp);
    gemm_nt<2><<<dim3(8, 16, 8), 256, 0, stream>>>(Pp, Vt, out, nullptr, nullptr, nullptr);
}

// Round 3
// 296.181 us; speedup vs baseline: 1.1377x; 1.1377x over previous
//
#include <hip/hip_runtime.h>
#include <hip/hip_bf16.h>

#define DI __device__ __forceinline__

typedef __bf16 bf16x8 __attribute__((ext_vector_type(8)));
typedef float  f32x4  __attribute__((ext_vector_type(4)));

DI unsigned short f2bf(float f) {
    unsigned int u = __float_as_uint(f);
    u += 0x7fffu + ((u >> 16) & 1u);
    return (unsigned short)(u >> 16);
}

DI void gload16(const unsigned short* g, unsigned short* l) {
    __builtin_amdgcn_global_load_lds(
        (const __attribute__((address_space(1))) unsigned int*)g,
        (__attribute__((address_space(3))) unsigned int*)l, 16, 0, 0);
}

// ---------------------------------------------------------------------------
__global__ void convert_x(const float* __restrict__ x, unsigned short* __restrict__ Xb) {
    int i = blockIdx.x * 256 + threadIdx.x;
    float4 v = reinterpret_cast<const float4*>(x)[i];
    ushort4 o;
    o.x = f2bf(v.x); o.y = f2bf(v.y); o.z = f2bf(v.z); o.w = f2bf(v.w);
    reinterpret_cast<ushort4*>(Xb)[i] = o;
}

__global__ void convert_w(const float* __restrict__ Wq, const float* __restrict__ Wk,
                          const float* __restrict__ Wv, unsigned short* __restrict__ Wt) {
    __shared__ float t[32][33];
    const int z = blockIdx.z;
    const float* W = (z == 0) ? Wq : (z == 1 ? Wk : Wv);
    const float scale = (z == 0) ? 0.03125f : 1.0f;
    const int n0 = blockIdx.x * 32, k0 = blockIdx.y * 32;
    const int tx = threadIdx.x, ty = threadIdx.y;
#pragma unroll
    for (int i = 0; i < 4; ++i)
        t[ty + i * 8][tx] = W[(size_t)(k0 + ty + i * 8) * 1024 + n0 + tx];
    __syncthreads();
#pragma unroll
    for (int i = 0; i < 4; ++i)
        Wt[(size_t)(z * 1024 + n0 + ty + i * 8) * 1024 + k0 + tx] =
            f2bf(t[tx][ty + i * 8] * scale);
}

// ---------------------------------------------------------------------------
// 256x256x(BK=64) 8-phase NT GEMM, 8 waves (2M x 4N), 128 KiB LDS dbuf.
// Stage schedule per kt: p0 -> (kt+1,A,hi); p1 -> (kt+1,B,hi);
// p2 -> (kt+2,A,lo); p3 -> (kt+2,B,lo); vmcnt(4) once per K-tile at p3.
// TAIL FIX (round 3): when kt+2 >= NT the p2/p3 stages are skipped, so only
// 8 loads are outstanding at p3 and vmcnt(4) would leave kt+1's hi-halves
// in flight when kt+1 reads them -> race. Drain vmcnt(0) once prefetch stops.
// ---------------------------------------------------------------------------

#define BAR    asm volatile("s_barrier" ::: "memory")
#define WAITV4 asm volatile("s_waitcnt vmcnt(4)" ::: "memory")
#define WAITV0 asm volatile("s_waitcnt vmcnt(0)" ::: "memory")

#define READ_A(SLOT, MH)                                                      \
    _Pragma("unroll")                                                         \
    for (int fi = 0; fi < 4; ++fi) {                                          \
        int r_ = wm * 64 + fi * 16 + lr;                                      \
        _Pragma("unroll")                                                     \
        for (int kk = 0; kk < 2; ++kk) {                                      \
            int ch_ = (kk * 4 + lg) ^ (r_ & 7);                               \
            aR[fi][kk] = *reinterpret_cast<const bf16x8*>(                    \
                lsA + ((SLOT) * 2 + (MH)) * 8192 + r_ * 64 + ch_ * 8);        \
        }                                                                     \
    }

#define READ_B(SLOT, NH, BS)                                                  \
    _Pragma("unroll")                                                         \
    for (int fj = 0; fj < 2; ++fj) {                                          \
        int r_ = wn * 32 + fj * 16 + lr;                                      \
        _Pragma("unroll")                                                     \
        for (int kk = 0; kk < 2; ++kk) {                                      \
            int ch_ = (kk * 4 + lg) ^ (r_ & 7);                               \
            BS[fj][kk] = *reinterpret_cast<const bf16x8*>(                    \
                lsB + ((SLOT) * 2 + (NH)) * 8192 + r_ * 64 + ch_ * 8);        \
        }                                                                     \
    }

#define STAGE_A(KT, H)                                                        \
    _Pragma("unroll")                                                         \
    for (int it = 0; it < 2; ++it) {                                          \
        int idx_ = it * 512 + tid;                                            \
        int row_ = idx_ >> 3;                                                 \
        int ch_ = (idx_ & 7) ^ (row_ & 7);                                    \
        const unsigned short* g_;                                             \
        if constexpr (MODE == 2)                                              \
            g_ = Ab + ((size_t)((KT) >> 2)) * 65536 +                         \
                 (size_t)((H) * 128 + row_) * 256 + ((KT) & 3) * 64 + ch_ * 8;\
        else                                                                  \
            g_ = Ab + (size_t)(m0 + (H) * 128 + row_) * 1024 + (KT) * 64 +    \
                 ch_ * 8;                                                     \
        gload16(g_, lsA + (((KT) & 1) * 2 + (H)) * 8192 + idx_ * 8);          \
    }

#define STAGE_B(KT, H)                                                        \
    _Pragma("unroll")                                                         \
    for (int it = 0; it < 2; ++it) {                                          \
        int idx_ = it * 512 + tid;                                            \
        int row_ = idx_ >> 3;                                                 \
        int ch_ = (idx_ & 7) ^ (row_ & 7);                                    \
        const unsigned short* g_;                                             \
        if constexpr (MODE == 2)                                              \
            g_ = Bb + (size_t)(n0 + (H) * 128 + row_) * 2048 + (KT) * 64 +    \
                 ch_ * 8;                                                     \
        else                                                                  \
            g_ = Bb + (size_t)(n0 + (H) * 128 + row_) * 1024 + (KT) * 64 +    \
                 ch_ * 8;                                                     \
        gload16(g_, lsB + (((KT) & 1) * 2 + (H)) * 8192 + idx_ * 8);          \
    }

#define MMA_PHASE(MH, NH, BS)                                                 \
    __builtin_amdgcn_s_setprio(1);                                            \
    _Pragma("unroll")                                                         \
    for (int kk = 0; kk < 2; ++kk)                                            \
        _Pragma("unroll")                                                     \
        for (int fi = 0; fi < 4; ++fi)                                        \
            _Pragma("unroll")                                                 \
            for (int fj = 0; fj < 2; ++fj)                                    \
                acc[(MH) * 4 + fi][(NH) * 2 + fj] =                           \
                    __builtin_amdgcn_mfma_f32_16x16x32_bf16(                  \
                        aR[fi][kk], BS[fj][kk],                               \
                        acc[(MH) * 4 + fi][(NH) * 2 + fj], 0, 0, 0);          \
    __builtin_amdgcn_s_setprio(0);

template <int MODE>
__global__ __launch_bounds__(512) void gemm256(
    const unsigned short* __restrict__ A0, const unsigned short* __restrict__ B0,
    float* __restrict__ Cf,
    unsigned short* __restrict__ Oq, unsigned short* __restrict__ Ok,
    unsigned short* __restrict__ Ov)
{
    extern __shared__ char smem_raw[];
    unsigned short* lsA = (unsigned short*)smem_raw;            // 4 x 16 KiB halves
    unsigned short* lsB = lsA + 32768;                          // 4 x 16 KiB halves

    const int tid = threadIdx.x;
    const int lane = tid & 63;
    const int wid = tid >> 6;
    const int wm = wid >> 2, wn = wid & 3;
    const int lr = lane & 15, lg = lane >> 4;
    const int bz = blockIdx.z;

    int m0, n0, NT;
    const unsigned short *Ab, *Bb;
    size_t sbase = 0, obase = 0;

    if constexpr (MODE == 0) {
        m0 = blockIdx.x * 256; n0 = blockIdx.y * 256; NT = 16;
        Ab = A0; Bb = B0;
    } else if constexpr (MODE == 1) {
        const int c = blockIdx.x, r = blockIdx.y;
        if (c > r) return;
        m0 = r * 256; n0 = c * 256; NT = 16;
        Ab = A0 + (size_t)bz * 2097152u;
        Bb = B0 + (size_t)bz * 2097152u;
        sbase = ((size_t)bz * 36 + (size_t)(r * (r + 1) / 2) + c) * 65536u;
    } else {
        const int r = blockIdx.y;
        m0 = r * 256; n0 = blockIdx.x * 256; NT = 4 * (r + 1);
        Ab = A0 + ((size_t)bz * 36 + (size_t)(r * (r + 1) / 2)) * 65536u;
        Bb = B0 + (size_t)bz * 2097152u;
        obase = (size_t)bz * 2097152u;
    }

    f32x4 acc[8][4] = {};
    bf16x8 aR[4][2], b0[2][2], b1[2][2];

    // prologue: kt0 fully + kt1 A-lo/B-lo; vmcnt(4) leaves only kt1 partials
    STAGE_A(0, 0); STAGE_A(0, 1); STAGE_B(0, 0); STAGE_B(0, 1);
    STAGE_A(1, 0); STAGE_B(1, 0);
    WAITV4; BAR;

    for (int kt = 0; kt < NT; ++kt) {
        const int slot = kt & 1;
        const bool s1 = (kt + 1) < NT, s2 = (kt + 2) < NT;
        // phase 0: quadrant (A-lo, B-lo)
        READ_A(slot, 0); READ_B(slot, 0, b0);
        if (s1) { STAGE_A(kt + 1, 1); }
        BAR; MMA_PHASE(0, 0, b0); BAR;
        // phase 1: quadrant (A-lo, B-hi)
        READ_B(slot, 1, b1);
        if (s1) { STAGE_B(kt + 1, 1); }
        BAR; MMA_PHASE(0, 1, b1); BAR;
        // phase 2: quadrant (A-hi, B-lo)  [A-lo of slot now dead -> kt+2 A-lo]
        READ_A(slot, 1);
        if (s2) { STAGE_A(kt + 2, 0); }
        BAR; MMA_PHASE(1, 0, b0); BAR;
        // phase 3: quadrant (A-hi, B-hi)  [B-lo of slot now dead -> kt+2 B-lo]
        if (s2) {
            STAGE_B(kt + 2, 0);
            WAITV4;          // 12 outstanding -> drain 8: kt+1 fully resident
        } else {
            WAITV0;          // tail: no kt+2 prefetch -> must drain kt+1 hi
        }
        BAR; MMA_PHASE(1, 1, b1); BAR;
    }

    // epilogue: D frag layout col=lr, row=lg*4+r2
#pragma unroll
    for (int i = 0; i < 8; ++i) {
        const int rl = (i >> 2) * 128 + wm * 64 + (i & 3) * 16 + lg * 4;
#pragma unroll
        for (int j = 0; j < 4; ++j) {
            const int cl = (j >> 1) * 128 + wn * 32 + (j & 1) * 16 + lr;
            f32x4 v = acc[i][j];
            if constexpr (MODE == 0) {
                const int gm = m0 + rl;
                const int z = n0 >> 10;
                const int cin = (n0 & 1023) + cl;
                if (z == 2) {   // V stored transposed per batch: Vt[b][d][n]
                    const int b = gm >> 11, nib = gm & 2047;
                    ushort4 h;
                    h.x = f2bf(v[0]); h.y = f2bf(v[1]); h.z = f2bf(v[2]); h.w = f2bf(v[3]);
                    *reinterpret_cast<ushort4*>(
                        &Ov[(size_t)b * 2097152u + (size_t)cin * 2048 + nib]) = h;
                } else {
                    unsigned short* O = z ? Ok : Oq;
#pragma unroll
                    for (int r2 = 0; r2 < 4; ++r2)
                        O[(size_t)(gm + r2) * 1024 + cin] = f2bf(v[r2]);
                }
            } else if constexpr (MODE == 1) {
#pragma unroll
                for (int r2 = 0; r2 < 4; ++r2)
                    Cf[sbase + (size_t)(rl + r2) * 256 + cl] = v[r2];
            } else {
#pragma unroll
                for (int r2 = 0; r2 < 4; ++r2)
                    Cf[obase + (size_t)(m0 + rl + r2) * 1024 + (n0 + cl)] = v[r2];
            }
        }
    }
}

// ---------------------------------------------------------------------------
// row softmax over packed causal 256x256 S tiles -> packed bf16 P
// ---------------------------------------------------------------------------
__global__ __launch_bounds__(256) void softmax_rows(const float* __restrict__ Sp,
                                                    unsigned short* __restrict__ Pp) {
    const int R = blockIdx.x;
    const int b = blockIdx.y;
    const int rt = R >> 8;
    const size_t rowbase = ((size_t)b * 36 + (size_t)(rt * (rt + 1) / 2)) * 65536u +
                           (size_t)(R & 255) * 256;
    const int tid = threadIdx.x;
    const int kend = (rt + 1) << 8;

    float vals[8];
    float m = -3.0e38f;
    int cnt = 0;
    for (int k = tid; k < kend; k += 256) {
        float s = Sp[rowbase + (size_t)(k >> 8) * 65536u + (k & 255)];
        vals[cnt++] = s;
        if (k <= R) m = fmaxf(m, s);
    }
    __shared__ float red[4];
#pragma unroll
    for (int o = 32; o > 0; o >>= 1) m = fmaxf(m, __shfl_xor(m, o));
    if ((tid & 63) == 0) red[tid >> 6] = m;
    __syncthreads();
    m = fmaxf(fmaxf(red[0], red[1]), fmaxf(red[2], red[3]));
    __syncthreads();

    float l = 0.0f;
    cnt = 0;
    for (int k = tid; k < kend; k += 256) {
        float e = (k <= R) ? __expf(vals[cnt] - m) : 0.0f;
        vals[cnt] = e;
        ++cnt;
        l += e;
    }
#pragma unroll
    for (int o = 32; o > 0; o >>= 1) l += __shfl_xor(l, o);
    if ((tid & 63) == 0) red[tid >> 6] = l;
    __syncthreads();
    l = red[0] + red[1] + red[2] + red[3];
    const float inv = 1.0f / l;

    cnt = 0;
    for (int k = tid; k < kend; k += 256)
        Pp[rowbase + (size_t)(k >> 8) * 65536u + (k & 255)] = f2bf(vals[cnt++] * inv);
}

// ---------------------------------------------------------------------------
extern "C" void kernel_launch(void* const* d_in, const int* in_sizes, int n_in,
                              void* d_out, int out_size, void* d_ws, size_t ws_size,
                              hipStream_t stream) {
    const float* x  = (const float*)d_in[0];
    const float* Wq = (const float*)d_in[1];
    const float* Wk = (const float*)d_in[2];
    const float* Wv = (const float*)d_in[3];
    float* out = (float*)d_out;

    // layout (Sp overlays Xb/Wt, which are dead after gemm256<0>):
    char* base = (char*)d_ws;
    unsigned short* Qb = (unsigned short*)(base);
    unsigned short* Kb = (unsigned short*)(base + 33554432u);
    unsigned short* Vt = (unsigned short*)(base + 67108864u);
    unsigned short* Xb = (unsigned short*)(base + 100663296u);
    unsigned short* Wt = (unsigned short*)(base + 134217728u);
    float*          Sp = (float*)         (base + 100663296u);   // 75.5 MB
    unsigned short* Pp = (unsigned short*)(base + 176160768u);   // 37.7 MB

    hipFuncSetAttribute(reinterpret_cast<const void*>(&gemm256<0>),
                        hipFuncAttributeMaxDynamicSharedMemorySize, 131072);
    hipFuncSetAttribute(reinterpret_cast<const void*>(&gemm256<1>),
                        hipFuncAttributeMaxDynamicSharedMemorySize, 131072);
    hipFuncSetAttribute(reinterpret_cast<const void*>(&gemm256<2>),
                        hipFuncAttributeMaxDynamicSharedMemorySize, 131072);

    convert_x<<<16384, 256, 0, stream>>>(x, Xb);
    convert_w<<<dim3(32, 32, 3), dim3(32, 8), 0, stream>>>(Wq, Wk, Wv, Wt);
    gemm256<0><<<dim3(64, 12), 512, 131072, stream>>>(Xb, Wt, nullptr, Qb, Kb, Vt);
    gemm256<1><<<dim3(8, 8, 8), 512, 131072, stream>>>(Qb, Kb, Sp, nullptr, nullptr, nullptr);
    softmax_rows<<<dim3(2048, 8), 256, 0, stream>>>(Sp, Pp);
    gemm256<2><<<dim3(4, 8, 8), 512, 131072, stream>>>(Pp, Vt, out, nullptr, nullptr, nullptr);
}

// Round 4
// 284.124 us; speedup vs baseline: 1.1860x; 1.0424x over previous
//
#include <hip/hip_runtime.h>
#include <hip/hip_bf16.h>

#define DI __device__ __forceinline__

typedef __bf16 bf16x8 __attribute__((ext_vector_type(8)));
typedef float  f32x4  __attribute__((ext_vector_type(4)));

DI unsigned short f2bf(float f) {
    unsigned int u = __float_as_uint(f);
    u += 0x7fffu + ((u >> 16) & 1u);
    return (unsigned short)(u >> 16);
}

DI void gload16(const unsigned short* g, unsigned short* l) {
    __builtin_amdgcn_global_load_lds(
        (const __attribute__((address_space(1))) unsigned int*)g,
        (__attribute__((address_space(3))) unsigned int*)l, 16, 0, 0);
}

// ---------------------------------------------------------------------------
__global__ void convert_x(const float* __restrict__ x, unsigned short* __restrict__ Xb) {
    int i = blockIdx.x * 256 + threadIdx.x;
    float4 v = reinterpret_cast<const float4*>(x)[i];
    ushort4 o;
    o.x = f2bf(v.x); o.y = f2bf(v.y); o.z = f2bf(v.z); o.w = f2bf(v.w);
    reinterpret_cast<ushort4*>(Xb)[i] = o;
}

__global__ void convert_w(const float* __restrict__ Wq, const float* __restrict__ Wk,
                          const float* __restrict__ Wv, unsigned short* __restrict__ Wt) {
    __shared__ float t[32][33];
    const int z = blockIdx.z;
    const float* W = (z == 0) ? Wq : (z == 1 ? Wk : Wv);
    const float scale = (z == 0) ? 0.03125f : 1.0f;
    const int n0 = blockIdx.x * 32, k0 = blockIdx.y * 32;
    const int tx = threadIdx.x, ty = threadIdx.y;
#pragma unroll
    for (int i = 0; i < 4; ++i)
        t[ty + i * 8][tx] = W[(size_t)(k0 + ty + i * 8) * 1024 + n0 + tx];
    __syncthreads();
#pragma unroll
    for (int i = 0; i < 4; ++i)
        Wt[(size_t)(z * 1024 + n0 + ty + i * 8) * 1024 + k0 + tx] =
            f2bf(t[tx][ty + i * 8] * scale);
}

// ---------------------------------------------------------------------------
// 256x256x(BK=64) 4-phase NT GEMM, 8 waves (2M x 4N), 128 KiB LDS dbuf.
// ROUND 4: single barrier per phase [R_p; S_p; BAR; MFMA_p] so a wave's
// next-phase ds_reads are serviced while other waves MFMA. Stage-overwrite
// safety: each stage's target region's last ds_reads are >=1 full phase +
// barrier + lgkmcnt earlier (see ledger in session notes). vmcnt ledger:
// steady 4->12 outstanding, drain 8 at p3 (kt+1 resident); tail drains 0.
// Addressing: fragment LDS offsets = abase ^ (kk*32) + fi*1024 (elements),
// stage offsets = per-thread 32-bit const + uniform kt term.
// ---------------------------------------------------------------------------

#define BAR    asm volatile("s_barrier" ::: "memory")
#define WAITV4 asm volatile("s_waitcnt vmcnt(4)" ::: "memory")
#define WAITV0 asm volatile("s_waitcnt vmcnt(0)" ::: "memory")

#define READ_A(SLOT, MH)                                                      \
    _Pragma("unroll")                                                         \
    for (int fi = 0; fi < 4; ++fi)                                            \
        _Pragma("unroll")                                                     \
        for (int kk = 0; kk < 2; ++kk)                                        \
            aR[fi][kk] = *reinterpret_cast<const bf16x8*>(                    \
                lsA + (SLOT) * 16384 + (MH) * 8192 +                          \
                ((abase ^ (kk * 32)) + fi * 1024));

#define READ_B(SLOT, NH, BS)                                                  \
    _Pragma("unroll")                                                         \
    for (int fj = 0; fj < 2; ++fj)                                            \
        _Pragma("unroll")                                                     \
        for (int kk = 0; kk < 2; ++kk)                                        \
            BS[fj][kk] = *reinterpret_cast<const bf16x8*>(                    \
                lsB + (SLOT) * 16384 + (NH) * 8192 +                          \
                ((bbase ^ (kk * 32)) + fj * 1024));

#define STAGE_A(KT, H)                                                        \
    {                                                                         \
        unsigned uA_;                                                         \
        if constexpr (MODE == 2)                                              \
            uA_ = ((unsigned)((KT) >> 2)) * 65536u + (H) * 32768u +           \
                  ((KT) & 3) * 64u;                                           \
        else                                                                  \
            uA_ = (unsigned)(m0 + (H) * 128) * 1024u + (unsigned)(KT) * 64u;  \
        _Pragma("unroll")                                                     \
        for (int it = 0; it < 2; ++it)                                        \
            gload16(Ab + uA_ + sAoff[it],                                     \
                    lsA + (((KT) & 1) * 2 + (H)) * 8192 + it * 4096 + tid * 8);\
    }

#define STAGE_B(KT, H)                                                        \
    {                                                                         \
        unsigned uB_ = (unsigned)(n0 + (H) * 128) * STRB + (unsigned)(KT) * 64u;\
        _Pragma("unroll")                                                     \
        for (int it = 0; it < 2; ++it)                                        \
            gload16(Bb + uB_ + sBoff[it],                                     \
                    lsB + (((KT) & 1) * 2 + (H)) * 8192 + it * 4096 + tid * 8);\
    }

#define MMA_PHASE(MH, NH, BS)                                                 \
    __builtin_amdgcn_s_setprio(1);                                            \
    _Pragma("unroll")                                                         \
    for (int kk = 0; kk < 2; ++kk)                                            \
        _Pragma("unroll")                                                     \
        for (int fi = 0; fi < 4; ++fi)                                        \
            _Pragma("unroll")                                                 \
            for (int fj = 0; fj < 2; ++fj)                                    \
                acc[(MH) * 4 + fi][(NH) * 2 + fj] =                           \
                    __builtin_amdgcn_mfma_f32_16x16x32_bf16(                  \
                        aR[fi][kk], BS[fj][kk],                               \
                        acc[(MH) * 4 + fi][(NH) * 2 + fj], 0, 0, 0);          \
    __builtin_amdgcn_s_setprio(0);

template <int MODE>
__global__ __launch_bounds__(512) void gemm256(
    const unsigned short* __restrict__ A0, const unsigned short* __restrict__ B0,
    float* __restrict__ Cf,
    unsigned short* __restrict__ Oq, unsigned short* __restrict__ Ok,
    unsigned short* __restrict__ Ov)
{
    extern __shared__ char smem_raw[];
    unsigned short* lsA = (unsigned short*)smem_raw;            // 4 x 16 KiB halves
    unsigned short* lsB = lsA + 32768;                          // 4 x 16 KiB halves

    const int tid = threadIdx.x;
    const int lane = tid & 63;
    const int wid = tid >> 6;
    const int wm = wid >> 2, wn = wid & 3;
    const int lr = lane & 15, lg = lane >> 4;
    const int bz = blockIdx.z;

    constexpr unsigned STRB = (MODE == 2) ? 2048u : 1024u;

    int m0, n0, NT;
    const unsigned short *Ab, *Bb;
    size_t sbase = 0, obase = 0;

    if constexpr (MODE == 0) {
        m0 = blockIdx.x * 256; n0 = blockIdx.y * 256; NT = 16;
        Ab = A0; Bb = B0;
    } else if constexpr (MODE == 1) {
        const int c = blockIdx.x, r = blockIdx.y;
        if (c > r) return;
        m0 = r * 256; n0 = c * 256; NT = 16;
        Ab = A0 + (size_t)bz * 2097152u;
        Bb = B0 + (size_t)bz * 2097152u;
        sbase = ((size_t)bz * 36 + (size_t)(r * (r + 1) / 2) + c) * 65536u;
    } else {
        const int r = blockIdx.y;
        m0 = r * 256; n0 = blockIdx.x * 256; NT = 4 * (r + 1);
        Ab = A0 + ((size_t)bz * 36 + (size_t)(r * (r + 1) / 2)) * 65536u;
        Bb = B0 + (size_t)bz * 2097152u;
        obase = (size_t)bz * 2097152u;
    }

    // per-thread constant offsets -------------------------------------------
    // fragment reads: addr = base + (abase ^ kk*32) + fi*1024 (elements);
    // valid because (row&7) == (lr&7) for all fragment rows.
    const unsigned chm = (unsigned)(lg ^ (lr & 7));
    const unsigned abase = (unsigned)(wm * 64 + lr) * 64u + chm * 8u;
    const unsigned bbase = (unsigned)(wn * 32 + lr) * 64u + chm * 8u;
    // stage loads: global elem offset = uniform + sXoff[it]
    unsigned sAoff[2], sBoff[2];
#pragma unroll
    for (int it = 0; it < 2; ++it) {
        const unsigned idx = it * 512 + tid;
        const unsigned row = idx >> 3;
        const unsigned ch = (idx & 7) ^ (row & 7);
        sAoff[it] = row * ((MODE == 2) ? 256u : 1024u) + ch * 8u;
        sBoff[it] = row * STRB + ch * 8u;
    }

    f32x4 acc[8][4] = {};
    bf16x8 aR[4][2], b0[2][2], b1[2][2];

    // prologue: kt0 fully + kt1 lo halves; vmcnt(4) drains kt0
    STAGE_A(0, 0); STAGE_A(0, 1); STAGE_B(0, 0); STAGE_B(0, 1);
    STAGE_A(1, 0); STAGE_B(1, 0);
    WAITV4; BAR;

    for (int kt = 0; kt < NT; ++kt) {
        const int slot = kt & 1;
        const bool s1 = (kt + 1) < NT, s2 = (kt + 2) < NT;
        // phase 0: (A-lo, B-lo); stage kt+1 A-hi (slot^1, loose)
        READ_A(slot, 0); READ_B(slot, 0, b0);
        if (s1) { STAGE_A(kt + 1, 1); }
        BAR; MMA_PHASE(0, 0, b0);
        // phase 1: (A-lo, B-hi); stage kt+1 B-hi (slot^1, loose)
        READ_B(slot, 1, b1);
        if (s1) { STAGE_B(kt + 1, 1); }
        BAR; MMA_PHASE(0, 1, b1);
        // phase 2: (A-hi, B-lo); stage kt+2 A-lo (current slot; aLo reads
        // certified complete by BAR(p1) via MMA_PHASE(0,0)'s lgkmcnt)
        READ_A(slot, 1);
        if (s2) { STAGE_A(kt + 2, 0); }
        BAR; MMA_PHASE(1, 0, b0);
        // phase 3: (A-hi, B-hi); stage kt+2 B-lo (b0 reads certified by BAR(p2))
        if (s2) {
            STAGE_B(kt + 2, 0);
            WAITV4;          // drain 8: kt+1 fully resident, kt+2 lo in flight
        } else {
            WAITV0;          // tail: no kt+2 prefetch -> drain kt+1 hi
        }
        BAR; MMA_PHASE(1, 1, b1);
    }

    // epilogue: D frag layout col=lr, row=lg*4+r2
#pragma unroll
    for (int i = 0; i < 8; ++i) {
        const int rl = (i >> 2) * 128 + wm * 64 + (i & 3) * 16 + lg * 4;
#pragma unroll
        for (int j = 0; j < 4; ++j) {
            const int cl = (j >> 1) * 128 + wn * 32 + (j & 1) * 16 + lr;
            f32x4 v = acc[i][j];
            if constexpr (MODE == 0) {
                const int gm = m0 + rl;
                const int z = n0 >> 10;
                const int cin = (n0 & 1023) + cl;
                if (z == 2) {   // V stored transposed per batch: Vt[b][d][n]
                    const int b = gm >> 11, nib = gm & 2047;
                    ushort4 h;
                    h.x = f2bf(v[0]); h.y = f2bf(v[1]); h.z = f2bf(v[2]); h.w = f2bf(v[3]);
                    *reinterpret_cast<ushort4*>(
                        &Ov[(size_t)b * 2097152u + (size_t)cin * 2048 + nib]) = h;
                } else {
                    unsigned short* O = z ? Ok : Oq;
#pragma unroll
                    for (int r2 = 0; r2 < 4; ++r2)
                        O[(size_t)(gm + r2) * 1024 + cin] = f2bf(v[r2]);
                }
            } else if constexpr (MODE == 1) {
#pragma unroll
                for (int r2 = 0; r2 < 4; ++r2)
                    Cf[sbase + (size_t)(rl + r2) * 256 + cl] = v[r2];
            } else {
#pragma unroll
                for (int r2 = 0; r2 < 4; ++r2)
                    Cf[obase + (size_t)(m0 + rl + r2) * 1024 + (n0 + cl)] = v[r2];
            }
        }
    }
}

// ---------------------------------------------------------------------------
// row softmax over packed causal 256x256 S tiles -> packed bf16 P
// ---------------------------------------------------------------------------
__global__ __launch_bounds__(256) void softmax_rows(const float* __restrict__ Sp,
                                                    unsigned short* __restrict__ Pp) {
    const int R = blockIdx.x;
    const int b = blockIdx.y;
    const int rt = R >> 8;
    const size_t rowbase = ((size_t)b * 36 + (size_t)(rt * (rt + 1) / 2)) * 65536u +
                           (size_t)(R & 255) * 256;
    const int tid = threadIdx.x;
    const int kend = (rt + 1) << 8;

    float vals[8];
    float m = -3.0e38f;
    int cnt = 0;
    for (int k = tid; k < kend; k += 256) {
        float s = Sp[rowbase + (size_t)(k >> 8) * 65536u + (k & 255)];
        vals[cnt++] = s;
        if (k <= R) m = fmaxf(m, s);
    }
    __shared__ float red[4];
#pragma unroll
    for (int o = 32; o > 0; o >>= 1) m = fmaxf(m, __shfl_xor(m, o));
    if ((tid & 63) == 0) red[tid >> 6] = m;
    __syncthreads();
    m = fmaxf(fmaxf(red[0], red[1]), fmaxf(red[2], red[3]));
    __syncthreads();

    float l = 0.0f;
    cnt = 0;
    for (int k = tid; k < kend; k += 256) {
        float e = (k <= R) ? __expf(vals[cnt] - m) : 0.0f;
        vals[cnt] = e;
        ++cnt;
        l += e;
    }
#pragma unroll
    for (int o = 32; o > 0; o >>= 1) l += __shfl_xor(l, o);
    if ((tid & 63) == 0) red[tid >> 6] = l;
    __syncthreads();
    l = red[0] + red[1] + red[2] + red[3];
    const float inv = 1.0f / l;

    cnt = 0;
    for (int k = tid; k < kend; k += 256)
        Pp[rowbase + (size_t)(k >> 8) * 65536u + (k & 255)] = f2bf(vals[cnt++] * inv);
}

// ---------------------------------------------------------------------------
extern "C" void kernel_launch(void* const* d_in, const int* in_sizes, int n_in,
                              void* d_out, int out_size, void* d_ws, size_t ws_size,
                              hipStream_t stream) {
    const float* x  = (const float*)d_in[0];
    const float* Wq = (const float*)d_in[1];
    const float* Wk = (const float*)d_in[2];
    const float* Wv = (const float*)d_in[3];
    float* out = (float*)d_out;

    // layout (Sp overlays Xb/Wt, which are dead after gemm256<0>):
    char* base = (char*)d_ws;
    unsigned short* Qb = (unsigned short*)(base);
    unsigned short* Kb = (unsigned short*)(base + 33554432u);
    unsigned short* Vt = (unsigned short*)(base + 67108864u);
    unsigned short* Xb = (unsigned short*)(base + 100663296u);
    unsigned short* Wt = (unsigned short*)(base + 134217728u);
    float*          Sp = (float*)         (base + 100663296u);   // 75.5 MB
    unsigned short* Pp = (unsigned short*)(base + 176160768u);   // 37.7 MB

    hipFuncSetAttribute(reinterpret_cast<const void*>(&gemm256<0>),
                        hipFuncAttributeMaxDynamicSharedMemorySize, 131072);
    hipFuncSetAttribute(reinterpret_cast<const void*>(&gemm256<1>),
                        hipFuncAttributeMaxDynamicSharedMemorySize, 131072);
    hipFuncSetAttribute(reinterpret_cast<const void*>(&gemm256<2>),
                        hipFuncAttributeMaxDynamicSharedMemorySize, 131072);

    convert_x<<<16384, 256, 0, stream>>>(x, Xb);
    convert_w<<<dim3(32, 32, 3), dim3(32, 8), 0, stream>>>(Wq, Wk, Wv, Wt);
    gemm256<0><<<dim3(64, 12), 512, 131072, stream>>>(Xb, Wt, nullptr, Qb, Kb, Vt);
    gemm256<1><<<dim3(8, 8, 8), 512, 131072, stream>>>(Qb, Kb, Sp, nullptr, nullptr, nullptr);
    softmax_rows<<<dim3(2048, 8), 256, 0, stream>>>(Sp, Pp);
    gemm256<2><<<dim3(4, 8, 8), 512, 131072, stream>>>(Pp, Vt, out, nullptr, nullptr, nullptr);
}